// Round 9
// baseline (591.640 us; speedup 1.0000x reference)
//
#include <hip/hip_runtime.h>

// WECT R8: NO LDS atomics. R4-R7 invariant: 1M ds_add_f32 wave-instrs = 334-346us
// regardless of gather structure or banking -> LDS atomic pipe ~213cy/wave-instr
// (~3.3cy/lane RMW) is the floor. R8 uses WAVE-PRIVATE histograms (block = 1 wave,
// hist[64][264] = 67.6KB, 2 blocks/CU) with non-atomic batched ds_read/ds_write:
// batch-of-8 RMW made safe by 28-pair in-register dedupe (merge same-bin weights,
// redirect dups to pad cols 256..263). Rotation (b+lane)&255 keeps banks spread
// (stride 264 -> bank (9*lane+b)%32, all 32 banks, 2 lanes each).

#define HGT 256
#define NDIR 64
#define NBINS (HGT * NDIR)
#define HPAD 264
#define HSIZE (NDIR * HPAD)
#define VGRID 256
#define SGRID 512

__global__ void wect_maxnorm(const float* __restrict__ vc, int k0,
                             unsigned* __restrict__ maxbits) {
    float m = 0.f;
    for (int i = blockIdx.x * blockDim.x + threadIdx.x; i < k0;
         i += gridDim.x * blockDim.x) {
        float x = vc[3 * i], y = vc[3 * i + 1], z = vc[3 * i + 2];
        m = fmaxf(m, sqrtf(x * x + y * y + z * z));
    }
    for (int off = 32; off > 0; off >>= 1)
        m = fmaxf(m, __shfl_down(m, off, 64));
    __shared__ float sm[16];
    int wid = threadIdx.x >> 6, lane = threadIdx.x & 63;
    if (lane == 0) sm[wid] = m;
    __syncthreads();
    if (threadIdx.x == 0) {
        float b = sm[0];
        int nw = blockDim.x >> 6;
        for (int w = 1; w < nw; ++w) b = fmaxf(b, sm[w]);
        atomicMax(maxbits, __float_as_uint(b));  // valid: all values >= 0
    }
}

__device__ __forceinline__ int height_bin(float h, float mh, float inv) {
    int idx = (int)ceilf((255.0f * (mh + h)) * inv);
    return min(max(idx, 0), HGT - 1);
}

// batched non-atomic RMW of 8 (addresses made distinct by dedupe)
__device__ __forceinline__ void rmw8(float* H, int lane, int* a, float* w) {
#pragma unroll
    for (int j = 1; j < 8; ++j)
#pragma unroll
        for (int k = 0; k < j; ++k) {
            bool dup = (a[j] == a[k]);
            w[k] += dup ? w[j] : 0.f;
            w[j] = dup ? 0.f : w[j];
            a[j] = dup ? lane * HPAD + 256 + j : a[j];
        }
    float v[8];
#pragma unroll
    for (int j = 0; j < 8; ++j) v[j] = H[a[j]];
#pragma unroll
    for (int j = 0; j < 8; ++j) H[a[j]] = v[j] + w[j];
}

// un-rotate hist -> part slot (64 threads)
__device__ __forceinline__ void flush3(const float* hist,
                                       float* __restrict__ dst) {
    for (int t = threadIdx.x; t < NBINS; t += 64) {
        int d = t >> 8, b = t & 255;
        dst[t] = hist[d * HPAD + ((b + d) & 255)];
    }
}

__global__ __launch_bounds__(64) void wect_vertex3(
    const float* __restrict__ vc, const float* __restrict__ vw,
    const float* __restrict__ dirs, int k0,
    const unsigned* __restrict__ maxbits, unsigned char* __restrict__ tab,
    float* __restrict__ part) {
    __shared__ float hist[HSIZE];
    int lane = threadIdx.x;
    for (int t = lane; t < HSIZE; t += 64) hist[t] = 0.f;
    float d0 = dirs[lane * 3], d1 = dirs[lane * 3 + 1], d2 = dirs[lane * 3 + 2];
    float mh = __uint_as_float(*maxbits);
    float inv = 1.0f / (2.0f * mh);
    int gw = blockIdx.x;
    for (int s0 = gw * 8; s0 < k0; s0 += VGRID * 8) {
        int a[8];
        float w[8];
#pragma unroll
        for (int j = 0; j < 8; ++j) {
            int s = min(s0 + j, k0 - 1);
            float x = vc[3 * s], y = vc[3 * s + 1], z = vc[3 * s + 2];
            float h = fmaf(x, d0, fmaf(y, d1, z * d2));
            int b = height_bin(h, mh, inv);
            tab[(size_t)s * 64 + lane] = (unsigned char)b;
            a[j] = lane * HPAD + ((b + lane) & 255);
            w[j] = (s0 + j < k0) ? vw[s] : 0.f;
        }
        rmw8(hist, lane, a, w);
    }
    __syncthreads();
    flush3(hist, part + (size_t)blockIdx.x * NBINS);
}

__global__ __launch_bounds__(64) void wect_simplex3(
    const int2* __restrict__ edges, const float* __restrict__ ew,
    const int* __restrict__ tris, const float* __restrict__ tw, int k1, int k2,
    const unsigned char* __restrict__ tab, float* __restrict__ part) {
    __shared__ float hist[HSIZE];
    int lane = threadIdx.x;
    for (int t = lane; t < HSIZE; t += 64) hist[t] = 0.f;
    int gw = blockIdx.x;

    // ---- edges: +w, max over 2 endpoints; gather-batch 16, RMW 2x8 ----
    for (int s0 = gw * 16; s0 < k1; s0 += SGRID * 16) {
        int va[16], vb[16];
        float w[16];
#pragma unroll
        for (int j = 0; j < 16; ++j) {
            int s = min(s0 + j, k1 - 1);  // uniform -> scalar loads
            int2 e = edges[s];
            va[j] = e.x;
            vb[j] = e.y;
            w[j] = (s0 + j < k1) ? ew[s] : 0.f;
        }
        unsigned A[16], B[16];
#pragma unroll
        for (int j = 0; j < 16; ++j) {
            A[j] = tab[(size_t)va[j] * 64 + lane];
            B[j] = tab[(size_t)vb[j] * 64 + lane];
        }
#pragma unroll
        for (int h = 0; h < 2; ++h) {
            int a[8];
            float ww[8];
#pragma unroll
            for (int j = 0; j < 8; ++j) {
                int m = max((int)A[h * 8 + j], (int)B[h * 8 + j]);
                a[j] = lane * HPAD + ((m + lane) & 255);
                ww[j] = w[h * 8 + j];
            }
            rmw8(hist, lane, a, ww);
        }
    }

    // ---- triangles: -w, max over 3 endpoints; batch 8 ----
    for (int s0 = gw * 8; s0 < k2; s0 += SGRID * 8) {
        int v0[8], v1[8], v2[8];
        float w[8];
#pragma unroll
        for (int j = 0; j < 8; ++j) {
            int s = min(s0 + j, k2 - 1);  // uniform -> scalar loads
            v0[j] = tris[3 * s];
            v1[j] = tris[3 * s + 1];
            v2[j] = tris[3 * s + 2];
            w[j] = (s0 + j < k2) ? -tw[s] : 0.f;
        }
        unsigned A[8], B[8], C[8];
#pragma unroll
        for (int j = 0; j < 8; ++j) {
            A[j] = tab[(size_t)v0[j] * 64 + lane];
            B[j] = tab[(size_t)v1[j] * 64 + lane];
            C[j] = tab[(size_t)v2[j] * 64 + lane];
        }
        int a[8];
#pragma unroll
        for (int j = 0; j < 8; ++j) {
            int m = max((int)A[j], max((int)B[j], (int)C[j]));
            a[j] = lane * HPAD + ((m + lane) & 255);
        }
        rmw8(hist, lane, a, w);
    }

    __syncthreads();
    flush3(hist, part + (size_t)blockIdx.x * NBINS);
}

// Sum partial histograms (nslots x NBINS) and cumsum over heights -> out.
__global__ __launch_bounds__(1024) void wect_reduce_cumsum(
    const float* __restrict__ part, int nslots, float* __restrict__ out) {
    __shared__ float lds[4 * HGT];
    int d = blockIdx.x;
    int tid = threadIdx.x;
    int b = tid & 255, g = tid >> 8;
    float acc = 0.f;
    for (int p = g; p < nslots; p += 4)
        acc += part[(size_t)p * NBINS + d * HGT + b];
    lds[tid] = acc;
    __syncthreads();
    float s = 0.f;
    if (tid < 256)
        s = lds[tid] + lds[tid + 256] + lds[tid + 512] + lds[tid + 768];
    __syncthreads();
    if (tid < 256) lds[tid] = s;
    __syncthreads();
    for (int off = 1; off < 256; off <<= 1) {
        float t = 0.f;
        if (tid < 256 && tid >= off) t = lds[tid - off];
        __syncthreads();
        if (tid < 256) lds[tid] += t;
        __syncthreads();
    }
    if (tid < 256) out[d * HGT + tid] = lds[tid];
}

// cumsum for fallback path
__global__ void wect_cumsum(float* __restrict__ out) {
    int lane = threadIdx.x;
    float4* row = (float4*)out + (size_t)blockIdx.x * 64;
    float4 v = row[lane];
    v.y += v.x;
    v.z += v.y;
    v.w += v.z;
    float s = v.w;
    float mine = s;
    for (int off = 1; off < 64; off <<= 1) {
        float t = __shfl_up(s, off, 64);
        if (lane >= off) s += t;
    }
    float excl = s - mine;
    v.x += excl;
    v.y += excl;
    v.z += excl;
    v.w += excl;
    row[lane] = v;
}

// ---------------- fallback kernels (no workspace) ----------------

__global__ __launch_bounds__(512) void wect_simplex_rec(
    const int* __restrict__ edges, const float* __restrict__ ew,
    const int* __restrict__ tris, const float* __restrict__ tw, int k1, int k2,
    const float* __restrict__ vc, const float* __restrict__ dirs,
    const unsigned* __restrict__ maxbits, float* __restrict__ out) {
    __shared__ float hist[NBINS];
    for (int i = threadIdx.x; i < NBINS; i += blockDim.x) hist[i] = 0.f;
    int lane = threadIdx.x & 63;
    float d0 = dirs[lane * 3], d1 = dirs[lane * 3 + 1], d2 = dirs[lane * 3 + 2];
    float mh = __uint_as_float(*maxbits);
    float inv = 1.0f / (2.0f * mh);
    __syncthreads();
    int wid = (blockIdx.x * blockDim.x + threadIdx.x) >> 6;
    int nw = (gridDim.x * blockDim.x) >> 6;
    int total = k1 + k2;
    for (int s = wid; s < total; s += nw) {
        int idx;
        float w;
        if (s < k1) {
            int v0 = edges[2 * s], v1 = edges[2 * s + 1];
            float h0 = vc[3 * v0] * d0 + vc[3 * v0 + 1] * d1 + vc[3 * v0 + 2] * d2;
            float h1 = vc[3 * v1] * d0 + vc[3 * v1 + 1] * d1 + vc[3 * v1 + 2] * d2;
            idx = max(height_bin(h0, mh, inv), height_bin(h1, mh, inv));
            w = ew[s];
        } else {
            int t = s - k1;
            int v0 = tris[3 * t], v1 = tris[3 * t + 1], v2 = tris[3 * t + 2];
            float h0 = vc[3 * v0] * d0 + vc[3 * v0 + 1] * d1 + vc[3 * v0 + 2] * d2;
            float h1 = vc[3 * v1] * d0 + vc[3 * v1 + 1] * d1 + vc[3 * v1 + 2] * d2;
            float h2 = vc[3 * v2] * d0 + vc[3 * v2 + 1] * d1 + vc[3 * v2 + 2] * d2;
            idx = max(height_bin(h0, mh, inv),
                      max(height_bin(h1, mh, inv), height_bin(h2, mh, inv)));
            w = -tw[t];
        }
        atomicAdd(&hist[idx * NDIR + lane], w);
    }
    __syncthreads();
    for (int i = threadIdx.x; i < NBINS; i += blockDim.x) {
        float v = hist[i];
        if (v != 0.f) atomicAdd(&out[(i & 63) * HGT + (i >> 6)], v);
    }
}

__global__ __launch_bounds__(512) void wect_vertex_rec(
    const float* __restrict__ vc, const float* __restrict__ vw,
    const float* __restrict__ dirs, int k0,
    const unsigned* __restrict__ maxbits, float* __restrict__ out) {
    __shared__ float hist[NBINS];
    for (int i = threadIdx.x; i < NBINS; i += blockDim.x) hist[i] = 0.f;
    int lane = threadIdx.x & 63;
    float d0 = dirs[lane * 3], d1 = dirs[lane * 3 + 1], d2 = dirs[lane * 3 + 2];
    float mh = __uint_as_float(*maxbits);
    float inv = 1.0f / (2.0f * mh);
    __syncthreads();
    int wid = (blockIdx.x * blockDim.x + threadIdx.x) >> 6;
    int nw = (gridDim.x * blockDim.x) >> 6;
    for (int k = wid; k < k0; k += nw) {
        float h = vc[3 * k] * d0 + vc[3 * k + 1] * d1 + vc[3 * k + 2] * d2;
        int idx = height_bin(h, mh, inv);
        atomicAdd(&hist[idx * NDIR + lane], vw[k]);
    }
    __syncthreads();
    for (int i = threadIdx.x; i < NBINS; i += blockDim.x) {
        float v = hist[i];
        if (v != 0.f) atomicAdd(&out[(i & 63) * HGT + (i >> 6)], v);
    }
}

extern "C" void kernel_launch(void* const* d_in, const int* in_sizes, int n_in,
                              void* d_out, int out_size, void* d_ws,
                              size_t ws_size, hipStream_t stream) {
    const float* v_coords = (const float*)d_in[0];
    const float* v_weights = (const float*)d_in[1];
    const int* edges = (const int*)d_in[2];
    const float* e_weights = (const float*)d_in[3];
    const int* tris = (const int*)d_in[4];
    const float* t_weights = (const float*)d_in[5];
    const float* dirs = (const float*)d_in[6];
    // d_in[7] = num_heights (=256, hardcoded as HGT)

    int k0 = in_sizes[0] / 3;
    int k1 = in_sizes[2] / 2;
    int k2 = in_sizes[4] / 3;

    float* out = (float*)d_out;
    unsigned* maxbits = (unsigned*)d_ws;
    unsigned char* tab = (unsigned char*)d_ws + 64;

    size_t table_need = 64 + (size_t)k0 * 64;
    size_t part_off = (table_need + 255) & ~(size_t)255;
    size_t part_need =
        part_off + (size_t)(VGRID + SGRID) * NBINS * sizeof(float);
    float* part = (float*)((char*)d_ws + part_off);

    (void)hipMemsetAsync(d_ws, 0, 64, stream);

    wect_maxnorm<<<256, 256, 0, stream>>>(v_coords, k0, maxbits);

    if (ws_size >= part_need) {
        wect_vertex3<<<VGRID, 64, 0, stream>>>(v_coords, v_weights, dirs, k0,
                                               maxbits, tab, part);
        wect_simplex3<<<SGRID, 64, 0, stream>>>(
            (const int2*)edges, e_weights, tris, t_weights, k1, k2, tab,
            part + (size_t)VGRID * NBINS);
        wect_reduce_cumsum<<<NDIR, 1024, 0, stream>>>(part, VGRID + SGRID,
                                                      out);
    } else {
        (void)hipMemsetAsync(d_out, 0, (size_t)NBINS * sizeof(float), stream);
        wect_vertex_rec<<<512, 512, 0, stream>>>(v_coords, v_weights, dirs, k0,
                                                 maxbits, out);
        wect_simplex_rec<<<512, 512, 0, stream>>>(edges, e_weights, tris,
                                                  t_weights, k1, k2, v_coords,
                                                  dirs, maxbits, out);
        wect_cumsum<<<NDIR, 64, 0, stream>>>(out);
    }
}

// Round 10
// 357.732 us; speedup vs baseline: 1.6539x; 1.6539x over previous
//
#include <hip/hip_runtime.h>

// WECT R9: non-atomic LDS RMW at 8 waves/CU.
// R4-R7: exactly 1M ds_add_f32 wave-instrs -> 334-346us regardless of gather
// structure & banking => LDS atomic pipe ~213cy/wave-instr. R8 removed atomics
// but at 2 waves/CU (confounded; latency-starved, VALU 13%).
// R9: 4 groups x 16 dirs. Per-WAVE private hist [16][257] f32 = 16.4KB;
// 4-wave blocks (65.8KB LDS) x 2 blocks/CU = 8 waves/CU. Wave = 4 simplices
// (sub-groups) x 16 dirs. Intra-wave (dir,bin) collisions live only in the
// xor-quad {l,l^16,l^32,l^48}: 3-step shfl_xor dedupe (16/32/48) merges
// weights (upper lane donates, retargets pad col 256). Then plain
// ds_read/add/ds_write. Tables: per-group 16B rows (3.2MB, L2-resident via
// g=bid&3 XCD pinning). Flush: 4-wave sum + skip-zero global atomics.

#define HGT 256
#define NDIR 64
#define NBINS (HGT * NDIR)
#define NG 4
#define GD 16
#define PADH 257
#define WH (GD * PADH)  // 4112 floats per wave
#define TPB 256
#define NWV (TPB / 64)
#define VSL 128
#define SSL 128
#define UE 2
#define UT 2

__global__ void wect_maxnorm(const float* __restrict__ vc, int k0,
                             unsigned* __restrict__ maxbits) {
    float m = 0.f;
    for (int i = blockIdx.x * blockDim.x + threadIdx.x; i < k0;
         i += gridDim.x * blockDim.x) {
        float x = vc[3 * i], y = vc[3 * i + 1], z = vc[3 * i + 2];
        m = fmaxf(m, sqrtf(x * x + y * y + z * z));
    }
    for (int off = 32; off > 0; off >>= 1)
        m = fmaxf(m, __shfl_down(m, off, 64));
    __shared__ float sm[16];
    int wid = threadIdx.x >> 6, lane = threadIdx.x & 63;
    if (lane == 0) sm[wid] = m;
    __syncthreads();
    if (threadIdx.x == 0) {
        float b = sm[0];
        int nw = blockDim.x >> 6;
        for (int w = 1; w < nw; ++w) b = fmaxf(b, sm[w]);
        atomicMax(maxbits, __float_as_uint(b));  // valid: all values >= 0
    }
}

__device__ __forceinline__ int height_bin(float h, float mh, float inv) {
    int idx = (int)ceilf((255.0f * (mh + h)) * inv);
    return min(max(idx, 0), HGT - 1);
}

// Merge same-address lanes within the xor-quad {l, l^16, l^32, l^48}.
// After this, all active (w!=0-bearing) addresses in the wave are distinct:
// collisions require same dir row (lane&15 equal) => same quad, all 6 pairs
// covered by masks 16,32,48. Upper lane of a matching pair donates w and
// retargets the (harmless) pad column.
__device__ __forceinline__ void dedupe4(int& a, float& w, int lane, int pad) {
#pragma unroll
    for (int m = 16; m <= 48; m += 16) {
        int pa = __shfl_xor(a, m, 64);
        float pw = __shfl_xor(w, m, 64);
        bool match = (pa == a);
        bool upper = lane > (lane ^ m);
        if (match) {
            if (upper) {
                w = 0.f;
                a = pad;
            } else {
                w += pw;
            }
        }
    }
}

__device__ __forceinline__ void flush4(const float* hist, int g,
                                       float* __restrict__ out) {
    for (int t = threadIdx.x; t < GD * HGT; t += TPB) {
        int d = t >> 8, b = t & 255;
        float s = 0.f;
#pragma unroll
        for (int u = 0; u < NWV; ++u) s += hist[u * WH + d * PADH + b];
        if (s != 0.f) atomicAdd(&out[(g * GD + d) * HGT + b], s);
    }
}

__global__ __launch_bounds__(TPB) void wect_vertex4(
    const float* __restrict__ vc, const float* __restrict__ vw,
    const float* __restrict__ dirs, int k0,
    const unsigned* __restrict__ maxbits, unsigned char* __restrict__ tab,
    float* __restrict__ out) {
    __shared__ float hist[NWV * WH];
    int tid = threadIdx.x, lane = tid & 63, wv = tid >> 6;
    int dl = lane & 15, sub = lane >> 4;
    for (int t = tid; t < NWV * WH; t += TPB) hist[t] = 0.f;
    int g = blockIdx.x & (NG - 1);
    int slice = blockIdx.x >> 2;
    int gd = g * GD + dl;
    float dx = dirs[3 * gd], dy = dirs[3 * gd + 1], dz = dirs[3 * gd + 2];
    float mh = __uint_as_float(*maxbits);
    float inv = 1.0f / (2.0f * mh);
    unsigned char* tabg = tab + (size_t)g * k0 * GD;
    float* H = hist + wv * WH;
    int pad = dl * PADH + 256;
    __syncthreads();
    int lo = (int)((long long)k0 * slice / VSL);
    int hi = (int)((long long)k0 * (slice + 1) / VSL);
    for (int s0 = lo + wv * 4; s0 < hi; s0 += NWV * 4) {
        int s = min(s0 + sub, hi - 1);
        bool act = (s0 + sub) < hi;
        float x = vc[3 * s], y = vc[3 * s + 1], z = vc[3 * s + 2];
        float w = act ? vw[s] : 0.f;
        float h = fmaf(x, dx, fmaf(y, dy, z * dz));
        int b = height_bin(h, mh, inv);
        if (act) tabg[(size_t)s * GD + dl] = (unsigned char)b;
        int a = dl * PADH + b;
        dedupe4(a, w, lane, pad);
        float v = H[a];
        H[a] = v + w;
    }
    __syncthreads();
    flush4(hist, g, out);
}

__global__ __launch_bounds__(TPB) void wect_simplex4(
    const int2* __restrict__ edges, const float* __restrict__ ew,
    const int* __restrict__ tris, const float* __restrict__ tw, int k1, int k2,
    const unsigned char* __restrict__ tab, int k0, float* __restrict__ out) {
    __shared__ float hist[NWV * WH];
    int tid = threadIdx.x, lane = tid & 63, wv = tid >> 6;
    int dl = lane & 15, sub = lane >> 4;
    for (int t = tid; t < NWV * WH; t += TPB) hist[t] = 0.f;
    int g = blockIdx.x & (NG - 1);
    int slice = blockIdx.x >> 2;
    const unsigned char* tabg = tab + (size_t)g * k0 * GD;
    float* H = hist + wv * WH;
    int pad = dl * PADH + 256;
    __syncthreads();

    // ---- edges: +w, max over 2 endpoints ----
    {
        int lo = (int)((long long)k1 * slice / SSL);
        int hi = (int)((long long)k1 * (slice + 1) / SSL);
        for (int s0 = lo + wv * 4 * UE; s0 < hi; s0 += NWV * 4 * UE) {
            int a_[UE];
            float w_[UE];
#pragma unroll
            for (int u = 0; u < UE; ++u) {
                int s = min(s0 + u * 4 + sub, hi - 1);
                bool act = (s0 + u * 4 + sub) < hi;
                int2 e = edges[s];
                float w = act ? ew[s] : 0.f;
                int A = tabg[(size_t)e.x * GD + dl];
                int B = tabg[(size_t)e.y * GD + dl];
                a_[u] = dl * PADH + max(A, B);
                w_[u] = w;
            }
#pragma unroll
            for (int u = 0; u < UE; ++u) {
                dedupe4(a_[u], w_[u], lane, pad);
                float v = H[a_[u]];
                H[a_[u]] = v + w_[u];
            }
        }
    }

    // ---- triangles: -w, max over 3 endpoints ----
    {
        int lo = (int)((long long)k2 * slice / SSL);
        int hi = (int)((long long)k2 * (slice + 1) / SSL);
        for (int s0 = lo + wv * 4 * UT; s0 < hi; s0 += NWV * 4 * UT) {
            int a_[UT];
            float w_[UT];
#pragma unroll
            for (int u = 0; u < UT; ++u) {
                int s = min(s0 + u * 4 + sub, hi - 1);
                bool act = (s0 + u * 4 + sub) < hi;
                int i0 = tris[3 * s], i1 = tris[3 * s + 1], i2 = tris[3 * s + 2];
                float w = act ? -tw[s] : 0.f;
                int A = tabg[(size_t)i0 * GD + dl];
                int B = tabg[(size_t)i1 * GD + dl];
                int C = tabg[(size_t)i2 * GD + dl];
                a_[u] = dl * PADH + max(A, max(B, C));
                w_[u] = w;
            }
#pragma unroll
            for (int u = 0; u < UT; ++u) {
                dedupe4(a_[u], w_[u], lane, pad);
                float v = H[a_[u]];
                H[a_[u]] = v + w_[u];
            }
        }
    }

    __syncthreads();
    flush4(hist, g, out);
}

__global__ void wect_cumsum(float* __restrict__ out) {
    // one wave (64 lanes) per direction row of 256 floats
    int lane = threadIdx.x;
    float4* row = (float4*)out + (size_t)blockIdx.x * 64;
    float4 v = row[lane];
    v.y += v.x;
    v.z += v.y;
    v.w += v.z;
    float s = v.w;
    float mine = s;
    for (int off = 1; off < 64; off <<= 1) {
        float t = __shfl_up(s, off, 64);
        if (lane >= off) s += t;
    }
    float excl = s - mine;
    v.x += excl;
    v.y += excl;
    v.z += excl;
    v.w += excl;
    row[lane] = v;
}

// ---------------- fallback kernels (no workspace) ----------------

__global__ __launch_bounds__(512) void wect_simplex_rec(
    const int* __restrict__ edges, const float* __restrict__ ew,
    const int* __restrict__ tris, const float* __restrict__ tw, int k1, int k2,
    const float* __restrict__ vc, const float* __restrict__ dirs,
    const unsigned* __restrict__ maxbits, float* __restrict__ out) {
    __shared__ float hist[NBINS];
    for (int i = threadIdx.x; i < NBINS; i += blockDim.x) hist[i] = 0.f;
    int lane = threadIdx.x & 63;
    float d0 = dirs[lane * 3], d1 = dirs[lane * 3 + 1], d2 = dirs[lane * 3 + 2];
    float mh = __uint_as_float(*maxbits);
    float inv = 1.0f / (2.0f * mh);
    __syncthreads();
    int wid = (blockIdx.x * blockDim.x + threadIdx.x) >> 6;
    int nw = (gridDim.x * blockDim.x) >> 6;
    int total = k1 + k2;
    for (int s = wid; s < total; s += nw) {
        int idx;
        float w;
        if (s < k1) {
            int v0 = edges[2 * s], v1 = edges[2 * s + 1];
            float h0 = vc[3 * v0] * d0 + vc[3 * v0 + 1] * d1 + vc[3 * v0 + 2] * d2;
            float h1 = vc[3 * v1] * d0 + vc[3 * v1 + 1] * d1 + vc[3 * v1 + 2] * d2;
            idx = max(height_bin(h0, mh, inv), height_bin(h1, mh, inv));
            w = ew[s];
        } else {
            int t = s - k1;
            int v0 = tris[3 * t], v1 = tris[3 * t + 1], v2 = tris[3 * t + 2];
            float h0 = vc[3 * v0] * d0 + vc[3 * v0 + 1] * d1 + vc[3 * v0 + 2] * d2;
            float h1 = vc[3 * v1] * d0 + vc[3 * v1 + 1] * d1 + vc[3 * v1 + 2] * d2;
            float h2 = vc[3 * v2] * d0 + vc[3 * v2 + 1] * d1 + vc[3 * v2 + 2] * d2;
            idx = max(height_bin(h0, mh, inv),
                      max(height_bin(h1, mh, inv), height_bin(h2, mh, inv)));
            w = -tw[t];
        }
        atomicAdd(&hist[idx * NDIR + lane], w);
    }
    __syncthreads();
    for (int i = threadIdx.x; i < NBINS; i += blockDim.x) {
        float v = hist[i];
        if (v != 0.f) atomicAdd(&out[(i & 63) * HGT + (i >> 6)], v);
    }
}

__global__ __launch_bounds__(512) void wect_vertex_rec(
    const float* __restrict__ vc, const float* __restrict__ vw,
    const float* __restrict__ dirs, int k0,
    const unsigned* __restrict__ maxbits, float* __restrict__ out) {
    __shared__ float hist[NBINS];
    for (int i = threadIdx.x; i < NBINS; i += blockDim.x) hist[i] = 0.f;
    int lane = threadIdx.x & 63;
    float d0 = dirs[lane * 3], d1 = dirs[lane * 3 + 1], d2 = dirs[lane * 3 + 2];
    float mh = __uint_as_float(*maxbits);
    float inv = 1.0f / (2.0f * mh);
    __syncthreads();
    int wid = (blockIdx.x * blockDim.x + threadIdx.x) >> 6;
    int nw = (gridDim.x * blockDim.x) >> 6;
    for (int k = wid; k < k0; k += nw) {
        float h = vc[3 * k] * d0 + vc[3 * k + 1] * d1 + vc[3 * k + 2] * d2;
        int idx = height_bin(h, mh, inv);
        atomicAdd(&hist[idx * NDIR + lane], vw[k]);
    }
    __syncthreads();
    for (int i = threadIdx.x; i < NBINS; i += blockDim.x) {
        float v = hist[i];
        if (v != 0.f) atomicAdd(&out[(i & 63) * HGT + (i >> 6)], v);
    }
}

extern "C" void kernel_launch(void* const* d_in, const int* in_sizes, int n_in,
                              void* d_out, int out_size, void* d_ws,
                              size_t ws_size, hipStream_t stream) {
    const float* v_coords = (const float*)d_in[0];
    const float* v_weights = (const float*)d_in[1];
    const int* edges = (const int*)d_in[2];
    const float* e_weights = (const float*)d_in[3];
    const int* tris = (const int*)d_in[4];
    const float* t_weights = (const float*)d_in[5];
    const float* dirs = (const float*)d_in[6];
    // d_in[7] = num_heights (=256, hardcoded as HGT)

    int k0 = in_sizes[0] / 3;
    int k1 = in_sizes[2] / 2;
    int k2 = in_sizes[4] / 3;

    float* out = (float*)d_out;
    unsigned* maxbits = (unsigned*)d_ws;
    unsigned char* tab = (unsigned char*)d_ws + 64;
    bool have_table = ws_size >= 64 + (size_t)NG * k0 * GD;

    (void)hipMemsetAsync(d_ws, 0, 64, stream);
    (void)hipMemsetAsync(d_out, 0, (size_t)NBINS * sizeof(float), stream);

    wect_maxnorm<<<256, 256, 0, stream>>>(v_coords, k0, maxbits);

    if (have_table) {
        wect_vertex4<<<NG * VSL, TPB, 0, stream>>>(v_coords, v_weights, dirs,
                                                   k0, maxbits, tab, out);
        wect_simplex4<<<NG * SSL, TPB, 0, stream>>>(
            (const int2*)edges, e_weights, tris, t_weights, k1, k2, tab, k0,
            out);
    } else {
        wect_vertex_rec<<<512, 512, 0, stream>>>(v_coords, v_weights, dirs, k0,
                                                 maxbits, out);
        wect_simplex_rec<<<512, 512, 0, stream>>>(edges, e_weights, tris,
                                                  t_weights, k1, k2, v_coords,
                                                  dirs, maxbits, out);
    }
    wect_cumsum<<<NDIR, 64, 0, stream>>>(out);
}